// Round 6
// baseline (416.738 us; speedup 1.0000x reference)
//
#include <hip/hip_runtime.h>

#define BB 128
#define TT 256
#define DDIM 64
#define NDP 516        // diag slots; 0..510 real, 511..515 pads (masked lanes only)
#define BIGF 1e10f
#define NEGB -1e12f
#define KE 144.2695040889f     // 1/(gamma*ln2)
#define GLN2 0.0069314718056f  // gamma*ln2  (R = R' * GLN2)

// Diagonal-layout scratch: [b][diag][row]. All values K-scaled.
__device__ float  g_D [(size_t)BB * NDP * TT];   // D' = K*D
__device__ float2 g_RD[(size_t)BB * NDP * TT];   // {R', A' = R'-D'}
__device__ float  g_sumE[BB];
__device__ float  g_sumEw[BB];

__device__ __forceinline__ float ex2(float x){ float r; asm("v_exp_f32 %0, %1":"=v"(r):"v"(x)); return r; }
__device__ __forceinline__ float lg2(float x){ float r; asm("v_log_f32 %0, %1":"=v"(r):"v"(x)); return r; }
__device__ __forceinline__ float min3f(float a,float b,float c){ float r; asm("v_min3_f32 %0,%1,%2,%3":"=v"(r):"v"(a),"v"(b),"v"(c)); return r; }
__device__ __forceinline__ float med3f(float a,float b,float c){ float r; asm("v_med3_f32 %0,%1,%2,%3":"=v"(r):"v"(a),"v"(b),"v"(c)); return r; }
__device__ __forceinline__ float max3f(float a,float b,float c){ float r; asm("v_max3_f32 %0,%1,%2,%3":"=v"(r):"v"(a),"v"(b),"v"(c)); return r; }

// ---------------------------------------------------------------------------
// Kernel 1: pairwise squared distances (K-scaled), diagonal layout.
// ---------------------------------------------------------------------------
__global__ __launch_bounds__(256) void dist_kernel(const float* __restrict__ P,
                                                   const float* __restrict__ Q) {
    const int rt = blockIdx.x;
    const int ct = blockIdx.y;
    const int b  = blockIdx.z;
    const int tid = threadIdx.x;

    __shared__ float Pl[64][68];
    __shared__ float Tl[64][68];

    const float* Pbase = P + ((size_t)b * TT + rt * 64) * DDIM;
    const float* Qbase = Q + ((size_t)b * TT + ct * 64) * DDIM;

#pragma unroll
    for (int it = 0; it < 4; ++it) {
        int e = (tid + it * 256) * 4;
        int r = e >> 6;
        int k = e & 63;
        float4 pv = *reinterpret_cast<const float4*>(Pbase + e);
        float4 qv = *reinterpret_cast<const float4*>(Qbase + e);
        Pl[k + 0][r] = pv.x; Pl[k + 1][r] = pv.y; Pl[k + 2][r] = pv.z; Pl[k + 3][r] = pv.w;
        Tl[k + 0][r] = qv.x; Tl[k + 1][r] = qv.y; Tl[k + 2][r] = qv.z; Tl[k + 3][r] = qv.w;
    }
    __syncthreads();

    const int r0 = (tid >> 4) * 4;
    const int c0 = (tid & 15) * 4;

    float acc[4][4] = {};
#pragma unroll
    for (int k = 0; k < 64; ++k) {
        float4 p = *reinterpret_cast<const float4*>(&Pl[k][r0]);
        float4 t = *reinterpret_cast<const float4*>(&Tl[k][c0]);
        float pa[4] = {p.x, p.y, p.z, p.w};
        float ta[4] = {t.x, t.y, t.z, t.w};
#pragma unroll
        for (int a = 0; a < 4; ++a)
#pragma unroll
            for (int c = 0; c < 4; ++c) {
                float df = pa[a] - ta[c];
                acc[a][c] = fmaf(df, df, acc[a][c]);
            }
    }

    float* Dg = g_D + (size_t)b * NDP * TT;
#pragma unroll
    for (int a = 0; a < 4; ++a)
#pragma unroll
        for (int c = 0; c < 4; ++c) {
            int i = rt * 64 + r0 + a;
            int j = ct * 64 + c0 + c;
            Dg[(size_t)(i + j) * TT + i] = acc[a][c] * KE;   // K-scaled
        }
}

// ---------------------------------------------------------------------------
// Kernel 2: fused soft-DTW fwd+bwd. One wave handles TWO batches (b, b+64)
// with interleaved ticks (independent work hides per-batch stalls).
// Systolic skew: lane l owns rows 4l..4l+3; tick t -> diag t-l.
// K-scaled domain: no multiplies by KE inside the recursions.
// ---------------------------------------------------------------------------
__global__ __launch_bounds__(64) void scan_kernel() {
    const int bA   = blockIdx.x;
    const int bBt  = blockIdx.x + 64;
    const int lane = threadIdx.x;
    const int row0 = lane << 2;
    const bool lane0  = (lane == 0);
    const bool lane63 = (lane == 63);

    const float* DbA  = g_D  + (size_t)bA  * NDP * TT;
    const float* DbB  = g_D  + (size_t)bBt * NDP * TT;
    float2*      RDbA = g_RD + (size_t)bA  * NDP * TT;
    float2*      RDbB = g_RD + (size_t)bBt * NDP * TT;

    // ---------------- forward ----------------
    float RAp1[4], RAp2[4], RBp1[4], RBp2[4];
#pragma unroll
    for (int r = 0; r < 4; ++r) { RAp1[r] = BIGF; RAp2[r] = BIGF; RBp1[r] = BIGF; RBp2[r] = BIGF; }
    float pfA[2] = {BIGF, BIGF}, pfB[2] = {BIGF, BIGF};
    float uA1 = BIGF, uA2 = BIGF, uB1 = BIGF, uB2 = BIGF;
    int dA = -lane, dB = -lane;

    auto loadDq = [&](const float* Db, int t) -> float4 {
        int d = t - lane;
        d = d < 0 ? 0 : (d > 515 ? 515 : d);
        return *reinterpret_cast<const float4*>(Db + (size_t)d * TT + row0);
    };

    auto FTICK = [&](float (&Rp1)[4], float (&Rp2)[4], float (&pf)[2],
                     float& u1, float& u2, int& dcur, float2* RDb,
                     const float4& dq, int kp) {
        u2 = u1;
        u1 = lane0 ? BIGF : pf[kp];
        const float dv[4] = {dq.x, dq.y, dq.z, dq.w};
        float Rn[4], st[8];
#pragma unroll
        for (int r = 0; r < 4; ++r) {
            const float z1 = (r == 0) ? u2 : Rp2[r - 1];
            const float z2 = (r == 0) ? u1 : Rp1[r - 1];
            const float z3 = Rp1[r];
            const float m  = min3f(z1, z2, z3);
            const float md = med3f(z1, z2, z3);
            const float mx = max3f(z1, z2, z3);
            const float s  = 1.0f + ex2(m - md) + ex2(m - mx);
            float rv = dv[r] + (m - lg2(s));
            if (r == 0) rv = (dcur == 0 && lane0) ? dv[0] : rv;
            const int j = dcur - (row0 + r);
            const bool valid = ((unsigned)j < 256u);
            Rn[r] = valid ? rv : BIGF;
            st[2 * r]     = Rn[r];
            st[2 * r + 1] = valid ? (rv - dv[r]) : NEGB;
        }
#pragma unroll
        for (int r = 0; r < 4; ++r) { Rp2[r] = Rp1[r]; Rp1[r] = Rn[r]; }
        pf[kp] = __shfl_up(Rp1[3], 1);
        if ((unsigned)dcur <= 510u) {
            float4* sp = reinterpret_cast<float4*>(RDb + (size_t)dcur * TT + row0);
            sp[0] = make_float4(st[0], st[1], st[2], st[3]);
            sp[1] = make_float4(st[4], st[5], st[6], st[7]);
        }
        ++dcur;
    };

    {
        float4 qaA[4], qaB[4], qbA[4], qbB[4];
#pragma unroll
        for (int k = 0; k < 4; ++k) { qaA[k] = loadDq(DbA, k); qaB[k] = loadDq(DbB, k); }
#pragma unroll 1
        for (int g = 0; g < 72; ++g) {      // 576 pair-ticks, groups of 8
            const int t0 = g * 8;
#pragma unroll
            for (int k = 0; k < 4; ++k) { qbA[k] = loadDq(DbA, t0 + 4 + k); qbB[k] = loadDq(DbB, t0 + 4 + k); }
            __builtin_amdgcn_sched_barrier(0);
#pragma unroll
            for (int k = 0; k < 4; ++k) {
                FTICK(RAp1, RAp2, pfA, uA1, uA2, dA, RDbA, qaA[k], k & 1);
                FTICK(RBp1, RBp2, pfB, uB1, uB2, dB, RDbB, qaB[k], k & 1);
            }
#pragma unroll
            for (int k = 0; k < 4; ++k) { qaA[k] = loadDq(DbA, t0 + 8 + k); qaB[k] = loadDq(DbB, t0 + 8 + k); }
            __builtin_amdgcn_sched_barrier(0);
#pragma unroll
            for (int k = 0; k < 4; ++k) {
                FTICK(RAp1, RAp2, pfA, uA1, uA2, dA, RDbA, qbA[k], k & 1);
                FTICK(RBp1, RBp2, pfB, uB1, uB2, dB, RDbB, qbB[k], k & 1);
            }
        }
    }

    asm volatile("s_waitcnt vmcnt(0)" ::: "memory");

    // ---------------- backward ----------------
    float EAp1[4], AAp1[4], EAp2[4], AAp2[4];
    float EBp1[4], ABp1[4], EBp2[4], ABp2[4];
#pragma unroll
    for (int r = 0; r < 4; ++r) {
        EAp1[r] = 0.0f; AAp1[r] = NEGB; EAp2[r] = 0.0f; AAp2[r] = NEGB;
        EBp1[r] = 0.0f; ABp1[r] = NEGB; EBp2[r] = 0.0f; ABp2[r] = NEGB;
    }
    float pfEA[2] = {0.0f, 0.0f}, pfAA[2] = {NEGB, NEGB};
    float pfEB[2] = {0.0f, 0.0f}, pfAB[2] = {NEGB, NEGB};
    float euA1 = 0.0f, auA1 = NEGB, euA2 = 0.0f, auA2 = NEGB;
    float euB1 = 0.0f, auB1 = NEGB, euB2 = 0.0f, auB2 = NEGB;
    float sEA = 0.0f, sWA = 0.0f, sEB = 0.0f, sWB = 0.0f;
    int dbA = 573 - lane, dbB = 573 - lane;

    auto loadRDq = [&](float2* RDb, int t, float4& lo, float4& hi) {
        int d = 573 - t - lane;
        d = d < 0 ? 0 : (d > 515 ? 515 : d);
        const float4* p = reinterpret_cast<const float4*>(RDb + (size_t)d * TT + row0);
        lo = p[0]; hi = p[1];
    };

    auto BTICK = [&](float (&Ep1)[4], float (&Ap1)[4], float (&Ep2)[4], float (&Ap2)[4],
                     float (&pfE)[2], float (&pfAr)[2],
                     float& eu1, float& au1, float& eu2, float& au2,
                     int& db, float& sumE, float& sumEw,
                     const float4& lo, const float4& hi, int kp) {
        eu2 = eu1; au2 = au1;
        eu1 = lane63 ? 0.0f : pfE[kp];
        au1 = lane63 ? NEGB : pfAr[kp];
        const float Rc[4] = {lo.x, lo.z, hi.x, hi.z};
        const float Ac[4] = {lo.y, lo.w, hi.y, hi.w};
        float En[4];
#pragma unroll
        for (int r = 0; r < 4; ++r) {
            const float mi  = Rc[r];          // already K-scaled
            const float s1e = (r < 3) ? Ep1[r + 1] : eu1;
            const float s1a = (r < 3) ? Ap1[r + 1] : au1;
            const float s2e = Ep1[r];
            const float s2a = Ap1[r];
            const float s3e = (r < 3) ? Ep2[r + 1] : eu2;
            const float s3a = (r < 3) ? Ap2[r + 1] : au2;
            float E = s1e * ex2(s1a - mi);
            E = fmaf(s2e, ex2(s2a - mi), E);
            E = fmaf(s3e, ex2(s3a - mi), E);
            if (r == 3) E = (db == 510 && lane63) ? 1.0f : E;
            En[r] = E;
        }
        const bool live = (db >= 0);
#pragma unroll
        for (int r = 0; r < 4; ++r) {
            const float Eg = live ? En[r] : 0.0f;
            sumE += Eg;
            const float w = (float)(2 * (row0 + r) - db);
            sumEw = fmaf(Eg * w, w, sumEw);
            Ep2[r] = Ep1[r]; Ap2[r] = Ap1[r];
            Ep1[r] = Eg;     Ap1[r] = Ac[r];
        }
        pfE[kp]  = __shfl_down(Ep1[0], 1);
        pfAr[kp] = __shfl_down(Ap1[0], 1);
        --db;
    };

    {
        float4 ralA[4], rahA[4], rblA[4], rbhA[4];
        float4 ralB[4], rahB[4], rblB[4], rbhB[4];
#pragma unroll
        for (int k = 0; k < 4; ++k) { loadRDq(RDbA, k, ralA[k], rahA[k]); loadRDq(RDbB, k, ralB[k], rahB[k]); }
#pragma unroll 1
        for (int g = 0; g < 72; ++g) {
            const int t0 = g * 8;
#pragma unroll
            for (int k = 0; k < 4; ++k) { loadRDq(RDbA, t0 + 4 + k, rblA[k], rbhA[k]); loadRDq(RDbB, t0 + 4 + k, rblB[k], rbhB[k]); }
            __builtin_amdgcn_sched_barrier(0);
#pragma unroll
            for (int k = 0; k < 4; ++k) {
                BTICK(EAp1, AAp1, EAp2, AAp2, pfEA, pfAA, euA1, auA1, euA2, auA2, dbA, sEA, sWA, ralA[k], rahA[k], k & 1);
                BTICK(EBp1, ABp1, EBp2, ABp2, pfEB, pfAB, euB1, auB1, euB2, auB2, dbB, sEB, sWB, ralB[k], rahB[k], k & 1);
            }
#pragma unroll
            for (int k = 0; k < 4; ++k) { loadRDq(RDbA, t0 + 8 + k, ralA[k], rahA[k]); loadRDq(RDbB, t0 + 8 + k, ralB[k], rahB[k]); }
            __builtin_amdgcn_sched_barrier(0);
#pragma unroll
            for (int k = 0; k < 4; ++k) {
                BTICK(EAp1, AAp1, EAp2, AAp2, pfEA, pfAA, euA1, auA1, euA2, auA2, dbA, sEA, sWA, rblA[k], rbhA[k], k & 1);
                BTICK(EBp1, ABp1, EBp2, ABp2, pfEB, pfAB, euB1, auB1, euB2, auB2, dbB, sEB, sWB, rblB[k], rbhB[k], k & 1);
            }
        }
    }

    // wave reductions
#pragma unroll
    for (int off = 32; off; off >>= 1) {
        sEA += __shfl_xor(sEA, off); sWA += __shfl_xor(sWA, off);
        sEB += __shfl_xor(sEB, off); sWB += __shfl_xor(sWB, off);
    }
    if (lane == 0) {
        g_sumE[bA]  = sEA; g_sumEw[bA]  = sWA;
        g_sumE[bBt] = sEB; g_sumEw[bBt] = sWB;
    }
}

// ---------------------------------------------------------------------------
// Kernel 3: finalize scalar loss.
// ---------------------------------------------------------------------------
__global__ __launch_bounds__(128) void fin_kernel(float* __restrict__ out) {
    __shared__ float rs[128];
    __shared__ float rt2[128];
    const int b = threadIdx.x;

    const float rfin = g_RD[((size_t)b * NDP + 510) * TT + (TT - 1)].x;  // R' scale
    const float shape = rfin * GLN2 * (1.0f / (float)TT);

    const float sE  = g_sumE[b]  * (1.0f / (float)TT);
    const float sEw = g_sumEw[b] * (1.0f / (float)TT) * (1.0f / (255.0f * 255.0f));
    const float temporal = sEw / fmaxf(sE, 1e-8f);

    rs[b]  = shape;
    rt2[b] = temporal;
    __syncthreads();
    for (int s = 64; s > 0; s >>= 1) {
        if (b < s) { rs[b] += rs[b + s]; rt2[b] += rt2[b + s]; }
        __syncthreads();
    }
    if (b == 0) {
        out[0] = 0.5f * (rs[0] * (1.0f / (float)BB)) + 0.5f * (rt2[0] * (1.0f / (float)BB));
    }
}

extern "C" void kernel_launch(void* const* d_in, const int* in_sizes, int n_in,
                              void* d_out, int out_size, void* d_ws, size_t ws_size,
                              hipStream_t stream) {
    (void)in_sizes; (void)n_in; (void)out_size; (void)d_ws; (void)ws_size;
    const float* preds   = (const float*)d_in[0];
    const float* targets = (const float*)d_in[1];
    float* out = (float*)d_out;

    dist_kernel<<<dim3(4, 4, BB), 256, 0, stream>>>(preds, targets);
    scan_kernel<<<64, 64, 0, stream>>>();
    fin_kernel<<<1, 128, 0, stream>>>(out);
}

// Round 8
// 297.925 us; speedup vs baseline: 1.3988x; 1.3988x over previous
//
#include <hip/hip_runtime.h>
#include <hip/hip_fp16.h>
#include <stdint.h>

#define BB 128
#define TT 256
#define DDIM 64
#define NDP 512          // diag slots 0..511 (511 = masked dummy, zeroed)
#define BIGF 1e10f
#define KE 144.2695040889f     // 1/(gamma*ln2)
#define GLN2 0.0069314718056f  // gamma*ln2 (R = R' * GLN2)

// [b][diag][row] layouts.
__device__ float    g_D[(size_t)BB * NDP * TT];   // D' = K*D
__device__ uint32_t g_W[(size_t)BB * NDP * TT];   // packed f16x2 {wu, wd}
__device__ float g_shape[BB], g_sumE[BB], g_sumEw[BB];

__device__ __forceinline__ float ex2(float x){ float r; asm("v_exp_f32 %0, %1":"=v"(r):"v"(x)); return r; }
__device__ __forceinline__ float lg2(float x){ float r; asm("v_log_f32 %0, %1":"=v"(r):"v"(x)); return r; }
__device__ __forceinline__ float min3f(float a,float b,float c){ float r; asm("v_min3_f32 %0,%1,%2,%3":"=v"(r):"v"(a),"v"(b),"v"(c)); return r; }

__device__ __forceinline__ uint32_t packw(float a, float b){
    auto h2 = __builtin_amdgcn_cvt_pkrtz(a, b);   // f32x2 -> f16x2
    union { decltype(h2) h; uint32_t u; } cv; cv.h = h2; return cv.u;
}
__device__ __forceinline__ float2 unpackw(uint32_t pk){
    union { uint32_t u; __half2 h; } cv; cv.u = pk;
    return __half22float2(cv.h);
}

// ---------------------------------------------------------------------------
// Kernel 1: pairwise squared distances (K-scaled), diagonal layout.
// Also zeroes dummy diag 511 so no uninitialized global is ever read.
// ---------------------------------------------------------------------------
__global__ __launch_bounds__(256) void dist_kernel(const float* __restrict__ P,
                                                   const float* __restrict__ Q) {
    const int rt = blockIdx.x;
    const int ct = blockIdx.y;
    const int b  = blockIdx.z;
    const int tid = threadIdx.x;

    __shared__ float Pl[64][68];
    __shared__ float Tl[64][68];

    const float* Pbase = P + ((size_t)b * TT + rt * 64) * DDIM;
    const float* Qbase = Q + ((size_t)b * TT + ct * 64) * DDIM;

#pragma unroll
    for (int it = 0; it < 4; ++it) {
        int e = (tid + it * 256) * 4;
        int r = e >> 6;
        int k = e & 63;
        float4 pv = *reinterpret_cast<const float4*>(Pbase + e);
        float4 qv = *reinterpret_cast<const float4*>(Qbase + e);
        Pl[k + 0][r] = pv.x; Pl[k + 1][r] = pv.y; Pl[k + 2][r] = pv.z; Pl[k + 3][r] = pv.w;
        Tl[k + 0][r] = qv.x; Tl[k + 1][r] = qv.y; Tl[k + 2][r] = qv.z; Tl[k + 3][r] = qv.w;
    }
    __syncthreads();

    const int r0 = (tid >> 4) * 4;
    const int c0 = (tid & 15) * 4;

    float acc[4][4] = {};
#pragma unroll
    for (int k = 0; k < 64; ++k) {
        float4 p = *reinterpret_cast<const float4*>(&Pl[k][r0]);
        float4 t = *reinterpret_cast<const float4*>(&Tl[k][c0]);
        float pa[4] = {p.x, p.y, p.z, p.w};
        float ta[4] = {t.x, t.y, t.z, t.w};
#pragma unroll
        for (int a = 0; a < 4; ++a)
#pragma unroll
            for (int c = 0; c < 4; ++c) {
                float df = pa[a] - ta[c];
                acc[a][c] = fmaf(df, df, acc[a][c]);
            }
    }

    float* Dg = g_D + (size_t)b * NDP * TT;
#pragma unroll
    for (int a = 0; a < 4; ++a)
#pragma unroll
        for (int c = 0; c < 4; ++c) {
            int i = rt * 64 + r0 + a;
            int j = ct * 64 + c0 + c;
            Dg[(size_t)(i + j) * TT + i] = acc[a][c] * KE;
        }
    if (rt == 0 && ct == 0) Dg[(size_t)511 * TT + tid] = 0.0f;   // dummy diag
}

// ---------------------------------------------------------------------------
// Kernel 2: fused soft-DTW fwd+bwd. One block (4 waves, 1 row/thread) per
// batch. Per-step traffic is LDS-only: D (fwd) and W (bwd) consumed from
// 16-diag strip double-buffers (4096 floats = 256 thr x 16 floats, exact
// cover), register-prefetched one strip ahead. Fwd stores only packed
// softmin-gradient weights {wu,wd} (f16x2, fire-and-forget: vmcnt is never
// drained inside the step loop). Per-step sync = s_barrier + lgkmcnt(0).
// ---------------------------------------------------------------------------
__global__ __launch_bounds__(256) void scan_kernel() {
    const int b    = blockIdx.x;
    const int tid  = threadIdx.x;
    const int w    = tid >> 6;
    const int lane = tid & 63;
    const int row  = tid;                 // global row 0..255
    const bool lane0  = (lane == 0);
    const bool lane63 = (lane == 63);

    const float* Db = g_D + (size_t)b * NDP * TT;
    uint32_t*    Wb = g_W + (size_t)b * NDP * TT;

    __shared__ float  Sbuf[2][16 * 256];  // 32 KB strip double-buffer
    __shared__ float  fr[4][4];           // fwd ring [diag&3][wave]
    __shared__ float2 br[4][4];           // bwd ring [diag&3][wave]
    __shared__ float  redE[4], redW[4];

    if (tid < 16) fr[tid & 3][tid >> 2] = BIGF;

    // ================= forward =================
    float rp1 = BIGF, rp2 = BIGF;         // own R' at diag d-1, d-2

    float4 pre0, pre1, pre2, pre3;        // next-strip staging (16 floats)
    {
        const float* src = Db + tid * 16;
        pre0 = *(const float4*)(src + 0);
        pre1 = *(const float4*)(src + 4);
        pre2 = *(const float4*)(src + 8);
        pre3 = *(const float4*)(src + 12);
    }

#pragma unroll 1
    for (int s = 0; s < 32; ++s) {        // 32 strips x 16 diags = 512 steps
        float* Bf = &Sbuf[s & 1][0];
        *(float4*)(Bf + tid * 16 + 0)  = pre0;
        *(float4*)(Bf + tid * 16 + 4)  = pre1;
        *(float4*)(Bf + tid * 16 + 8)  = pre2;
        *(float4*)(Bf + tid * 16 + 12) = pre3;
        {   // prefetch strip s+1 (clamped)
            const float* src = Db + (size_t)((s < 31) ? (s + 1) : 31) * 16 * TT + tid * 16;
            pre0 = *(const float4*)(src + 0);
            pre1 = *(const float4*)(src + 4);
            pre2 = *(const float4*)(src + 8);
            pre3 = *(const float4*)(src + 12);
        }
        asm volatile("s_waitcnt lgkmcnt(0)" ::: "memory");
        __builtin_amdgcn_sched_barrier(0);
        __builtin_amdgcn_s_barrier();

        float dcur = Bf[row];
#pragma unroll 1
        for (int k = 0; k < 16; ++k) {
            const int d = s * 16 + k;
            const int kk = (k < 15) ? (k + 1) : 15;
            float dnxt = Bf[kk * 256 + row];

            float rb1 = fr[(d - 1) & 3][(w == 0) ? 0 : (w - 1)];
            float rb2 = fr[(d - 2) & 3][(w == 0) ? 0 : (w - 1)];
            float up1 = __shfl_up(rp1, 1);
            float up2 = __shfl_up(rp2, 1);
            float z2 = lane0 ? ((w == 0) ? BIGF : rb1) : up1;   // R'[i-1][j]
            float z1 = lane0 ? ((w == 0) ? BIGF : rb2) : up2;   // R'[i-1][j-1]
            float z3 = rp1;                                     // R'[i][j-1]
            float m  = min3f(z1, z2, z3);
            float u1 = ex2(m - z1);        // diag-pred (unnorm)
            float u2 = ex2(m - z2);        // up-pred
            float u3 = ex2(m - z3);        // left-pred
            float ssum = u1 + u2 + u3;
            float rinv = __builtin_amdgcn_rcpf(ssum);
            float rv = dcur + (m - lg2(ssum));
            if (d == 0) rv = (row == 0) ? dcur : rv;            // R[0][0]=D[0][0]
            const int j = d - row;
            const bool valid = ((unsigned)j < 256u);
            float Rn = valid ? rv : BIGF;
            rp2 = rp1; rp1 = Rn;
            Wb[(size_t)d * TT + row] = packw(u2 * rinv, u1 * rinv);  // {wu, wd}
            if (lane63) fr[d & 3][w] = Rn;
            asm volatile("s_waitcnt lgkmcnt(0)" ::: "memory");
            __builtin_amdgcn_sched_barrier(0);
            __builtin_amdgcn_s_barrier();
            dcur = dnxt;
        }
    }

    if (row == 255) g_shape[b] = rp2;     // R'(255, 510)

    asm volatile("s_waitcnt vmcnt(0)" ::: "memory");  // all W stores retired
    __syncthreads();

    // ================= backward =================
    if (tid < 16) br[tid & 3][tid >> 2] = make_float2(0.0f, __uint_as_float(0u));

    float E1 = 0.0f, E2 = 0.0f, wl1 = 0.0f;
    uint32_t pk1 = 0u, pk2 = 0u;
    float sumE = 0.0f, sumEw = 0.0f;

    uint4 q0, q1, q2, q3;
    {
        const uint32_t* src = Wb + (size_t)31 * 16 * TT + tid * 16;
        q0 = *(const uint4*)(src + 0);
        q1 = *(const uint4*)(src + 4);
        q2 = *(const uint4*)(src + 8);
        q3 = *(const uint4*)(src + 12);
    }

#pragma unroll 1
    for (int s = 31; s >= 0; --s) {
        uint32_t* Bw = (uint32_t*)&Sbuf[s & 1][0];
        *(uint4*)(Bw + tid * 16 + 0)  = q0;
        *(uint4*)(Bw + tid * 16 + 4)  = q1;
        *(uint4*)(Bw + tid * 16 + 8)  = q2;
        *(uint4*)(Bw + tid * 16 + 12) = q3;
        {   // prefetch strip s-1 (clamped)
            const uint32_t* src = Wb + (size_t)((s > 0) ? (s - 1) : 0) * 16 * TT + tid * 16;
            q0 = *(const uint4*)(src + 0);
            q1 = *(const uint4*)(src + 4);
            q2 = *(const uint4*)(src + 8);
            q3 = *(const uint4*)(src + 12);
        }
        asm volatile("s_waitcnt lgkmcnt(0)" ::: "memory");
        __builtin_amdgcn_sched_barrier(0);
        __builtin_amdgcn_s_barrier();

        uint32_t pkcur = Bw[15 * 256 + row];
#pragma unroll 1
        for (int k = 15; k >= 0; --k) {
            const int d = s * 16 + k;
            const int kk = (k > 0) ? (k - 1) : 0;
            uint32_t pknxt = Bw[kk * 256 + row];

            float2 wcv = unpackw(pkcur);                 // {wu, wd} of own cell @ d
            float wl_c = 1.0f - wcv.x - wcv.y;
            int   pk1d = __shfl_down((int)pk1, 1);
            float E1d  = __shfl_down(E1, 1);
            int   pk2d = __shfl_down((int)pk2, 1);
            float E2d  = __shfl_down(E2, 1);
            if (lane63) {
                if (w < 3) {
                    float2 r1 = br[(d + 1) & 3][w + 1];
                    float2 r2 = br[(d + 2) & 3][w + 1];
                    E1d = r1.x; pk1d = (int)__float_as_uint(r1.y);
                    E2d = r2.x; pk2d = (int)__float_as_uint(r2.y);
                } else { E1d = 0.0f; E2d = 0.0f; pk1d = 0; pk2d = 0; }
            }
            float wu_s1 = unpackw((uint32_t)pk1d).x;     // wu of (i+1, j)   @ d+1
            float wd_s3 = unpackw((uint32_t)pk2d).y;     // wd of (i+1, j+1) @ d+2
            float E = E1d * wu_s1 + E1 * wl1 + E2d * wd_s3;
            const int j = d - row;
            E = ((unsigned)j < 256u) ? E : 0.0f;
            if (d == 510) E = (row == 255) ? 1.0f : 0.0f;   // seed (255,255)
            sumE += E;
            const float fw = (float)(2 * row - d);          // (i - j)
            sumEw = fmaf(E * fw, fw, sumEw);
            if (lane0) br[d & 3][w] = make_float2(E, __uint_as_float(pkcur));
            E2 = E1; pk2 = pk1;
            E1 = E;  pk1 = pkcur; wl1 = wl_c;
            asm volatile("s_waitcnt lgkmcnt(0)" ::: "memory");
            __builtin_amdgcn_sched_barrier(0);
            __builtin_amdgcn_s_barrier();
            pkcur = pknxt;
        }
    }

    // wave-local reduction, then 4 partials via LDS
#pragma unroll
    for (int off = 32; off; off >>= 1) {
        sumE  += __shfl_xor(sumE,  off);
        sumEw += __shfl_xor(sumEw, off);
    }
    if (lane == 0) { redE[w] = sumE; redW[w] = sumEw; }
    __syncthreads();
    if (tid == 0) {
        g_sumE[b]  = redE[0] + redE[1] + redE[2] + redE[3];
        g_sumEw[b] = redW[0] + redW[1] + redW[2] + redW[3];
    }
}

// ---------------------------------------------------------------------------
// Kernel 3: finalize scalar loss.
// ---------------------------------------------------------------------------
__global__ __launch_bounds__(128) void fin_kernel(float* __restrict__ out) {
    __shared__ float rs[128];
    __shared__ float rt2[128];
    const int b = threadIdx.x;

    const float shape = g_shape[b] * GLN2 * (1.0f / (float)TT);

    const float sE  = g_sumE[b]  * (1.0f / (float)TT);
    const float sEw = g_sumEw[b] * (1.0f / (float)TT) * (1.0f / (255.0f * 255.0f));
    const float temporal = sEw / fmaxf(sE, 1e-8f);

    rs[b]  = shape;
    rt2[b] = temporal;
    __syncthreads();
    for (int s = 64; s > 0; s >>= 1) {
        if (b < s) { rs[b] += rs[b + s]; rt2[b] += rt2[b + s]; }
        __syncthreads();
    }
    if (b == 0) {
        out[0] = 0.5f * (rs[0] * (1.0f / (float)BB)) + 0.5f * (rt2[0] * (1.0f / (float)BB));
    }
}

extern "C" void kernel_launch(void* const* d_in, const int* in_sizes, int n_in,
                              void* d_out, int out_size, void* d_ws, size_t ws_size,
                              hipStream_t stream) {
    (void)in_sizes; (void)n_in; (void)out_size; (void)d_ws; (void)ws_size;
    const float* preds   = (const float*)d_in[0];
    const float* targets = (const float*)d_in[1];
    float* out = (float*)d_out;

    dist_kernel<<<dim3(4, 4, BB), 256, 0, stream>>>(preds, targets);
    scan_kernel<<<BB, 256, 0, stream>>>();
    fin_kernel<<<1, 128, 0, stream>>>(out);
}

// Round 9
// 274.694 us; speedup vs baseline: 1.5171x; 1.0846x over previous
//
#include <hip/hip_runtime.h>
#include <hip/hip_fp16.h>
#include <stdint.h>

#define BB 128
#define TT 256
#define DDIM 64
#define NDQ 128                // 128 quad-diag groups = 512 diag slots (511 = dummy)
#define BIGF 1e10f
#define KE 144.2695040889f     // 1/(gamma*ln2)
#define GLN2 0.0069314718056f  // gamma*ln2 (R = R' * GLN2)

// [b][diag][row] layouts (K-scaled domain).
__device__ float g_D[(size_t)BB * 512 * TT];      // D' = K*D
__device__ uint4 g_W4[(size_t)BB * NDQ * TT];     // per row: 4 diags of packed f16x2 {wu, wd}
__device__ float g_shape[BB], g_sumE[BB], g_sumEw[BB];

__device__ __forceinline__ float ex2(float x){ float r; asm("v_exp_f32 %0, %1":"=v"(r):"v"(x)); return r; }
__device__ __forceinline__ float lg2(float x){ float r; asm("v_log_f32 %0, %1":"=v"(r):"v"(x)); return r; }
__device__ __forceinline__ float min3f(float a,float b,float c){ float r; asm("v_min3_f32 %0,%1,%2,%3":"=v"(r):"v"(a),"v"(b),"v"(c)); return r; }

__device__ __forceinline__ uint32_t packw(float a, float b){
    auto h2 = __builtin_amdgcn_cvt_pkrtz(a, b);
    union { decltype(h2) h; uint32_t u; } cv; cv.h = h2; return cv.u;
}
__device__ __forceinline__ float2 unpackw(uint32_t pk){
    union { uint32_t u; __half2 h; } cv; cv.u = pk;
    return __half22float2(cv.h);
}

// ---------------------------------------------------------------------------
// Kernel 1: pairwise squared distances (K-scaled), diagonal layout.
// ---------------------------------------------------------------------------
__global__ __launch_bounds__(256) void dist_kernel(const float* __restrict__ P,
                                                   const float* __restrict__ Q) {
    const int rt = blockIdx.x;
    const int ct = blockIdx.y;
    const int b  = blockIdx.z;
    const int tid = threadIdx.x;

    __shared__ float Pl[64][68];
    __shared__ float Tl[64][68];

    const float* Pbase = P + ((size_t)b * TT + rt * 64) * DDIM;
    const float* Qbase = Q + ((size_t)b * TT + ct * 64) * DDIM;

#pragma unroll
    for (int it = 0; it < 4; ++it) {
        int e = (tid + it * 256) * 4;
        int r = e >> 6;
        int k = e & 63;
        float4 pv = *reinterpret_cast<const float4*>(Pbase + e);
        float4 qv = *reinterpret_cast<const float4*>(Qbase + e);
        Pl[k + 0][r] = pv.x; Pl[k + 1][r] = pv.y; Pl[k + 2][r] = pv.z; Pl[k + 3][r] = pv.w;
        Tl[k + 0][r] = qv.x; Tl[k + 1][r] = qv.y; Tl[k + 2][r] = qv.z; Tl[k + 3][r] = qv.w;
    }
    __syncthreads();

    const int r0 = (tid >> 4) * 4;
    const int c0 = (tid & 15) * 4;

    float acc[4][4] = {};
#pragma unroll
    for (int k = 0; k < 64; ++k) {
        float4 p = *reinterpret_cast<const float4*>(&Pl[k][r0]);
        float4 t = *reinterpret_cast<const float4*>(&Tl[k][c0]);
        float pa[4] = {p.x, p.y, p.z, p.w};
        float ta[4] = {t.x, t.y, t.z, t.w};
#pragma unroll
        for (int a = 0; a < 4; ++a)
#pragma unroll
            for (int c = 0; c < 4; ++c) {
                float df = pa[a] - ta[c];
                acc[a][c] = fmaf(df, df, acc[a][c]);
            }
    }

    float* Dg = g_D + (size_t)b * 512 * TT;
#pragma unroll
    for (int a = 0; a < 4; ++a)
#pragma unroll
        for (int c = 0; c < 4; ++c) {
            int i = rt * 64 + r0 + a;
            int j = ct * 64 + c0 + c;
            Dg[(size_t)(i + j) * TT + i] = acc[a][c] * KE;
        }
    if (rt == 0 && ct == 0) Dg[(size_t)511 * TT + tid] = 0.0f;   // dummy diag
}

// ---------------------------------------------------------------------------
// Kernel 2: fused soft-DTW fwd+bwd. ONE WAVE per batch, rows 4l..4l+3 per
// lane, FOUR DIAGONALS per iteration (amortizes loop/VMEM/shuffle overhead).
// No LDS, no barriers. Boundary values via shfl with >=3-cell compute slack
// (raw results selected at use-site). Fwd stores packed f16x2 softmin
// gradients (uint4 = 4 diags); bwd is pure fma on them.
// ---------------------------------------------------------------------------
__global__ __launch_bounds__(64) void scan_kernel() {
    const int b    = blockIdx.x;
    const int lane = threadIdx.x;
    const int row0 = lane << 2;
    const bool lane0  = (lane == 0);
    const bool lane63 = (lane == 63);

    const float* Db = g_D  + (size_t)b * 512 * TT;
    uint4*       W4 = g_W4 + (size_t)b * NDQ * TT;

    // ================= forward =================
    float rp1[4], rp2[4];          // own rows' R' at d-1 / d-2
#pragma unroll
    for (int r = 0; r < 4; ++r) { rp1[r] = BIGF; rp2[r] = BIGF; }
    float u1r = BIGF;              // raw shfl: R'[row0-1] at d-1
    float u2v = BIGF;              // selected: R'[row0-1] at d-2

    auto LD = [&](int d) -> float4 {
        return *reinterpret_cast<const float4*>(Db + (size_t)d * TT + row0);
    };

    auto FBODY = [&](float4 (&q)[4], int it) {
        uint32_t wst[4][4];
#pragma unroll
        for (int qq = 0; qq < 4; ++qq) {
            const int d = it * 4 + qq;
            const float dv[4] = {q[qq].x, q[qq].y, q[qq].z, q[qq].w};
            float Rn[4];
#pragma unroll
            for (int r = 1; r < 4; ++r) {
                const float z1 = rp2[r - 1], z2 = rp1[r - 1], z3 = rp1[r];
                const float m  = min3f(z1, z2, z3);
                const float e1 = ex2(m - z1), e2 = ex2(m - z2), e3 = ex2(m - z3);
                const float ss = e1 + e2 + e3;
                const float rv = dv[r] + (m - lg2(ss));
                const float ri = __builtin_amdgcn_rcpf(ss);
                wst[r][qq] = packw(e2 * ri, e1 * ri);
                const bool valid = (unsigned)(d - (row0 + r)) < 256u;
                Rn[r] = valid ? rv : BIGF;
            }
            const float nx = __shfl_up(Rn[3], 1);   // consumed next diag (row0)
            {   // row 0 — consumes boundary values last (shfl slack)
                const float z1 = u2v;
                const float z2 = lane0 ? BIGF : u1r;
                const float z3 = rp1[0];
                const float m  = min3f(z1, z2, z3);
                const float e1 = ex2(m - z1), e2 = ex2(m - z2), e3 = ex2(m - z3);
                const float ss = e1 + e2 + e3;
                float rv = dv[0] + (m - lg2(ss));
                const float ri = __builtin_amdgcn_rcpf(ss);
                wst[0][qq] = packw(e2 * ri, e1 * ri);
                if (d == 0) rv = dv[0];             // R[0][0] = D[0][0]
                const bool valid = (unsigned)(d - row0) < 256u;
                Rn[0] = valid ? rv : BIGF;
            }
#pragma unroll
            for (int r = 0; r < 4; ++r) { rp2[r] = rp1[r]; rp1[r] = Rn[r]; }
            u2v = lane0 ? BIGF : u1r;
            u1r = nx;
        }
#pragma unroll
        for (int r = 0; r < 4; ++r)
            W4[(size_t)it * TT + row0 + r] =
                make_uint4(wst[r][0], wst[r][1], wst[r][2], wst[r][3]);
        const int itn = (it + 2 < NDQ) ? (it + 2) : (NDQ - 1);
#pragma unroll
        for (int qq = 0; qq < 4; ++qq) q[qq] = LD(itn * 4 + qq);
    };

    {
        float4 qa[4], qb[4];
#pragma unroll
        for (int qq = 0; qq < 4; ++qq) { qa[qq] = LD(qq); qb[qq] = LD(4 + qq); }
#pragma unroll 1
        for (int i2 = 0; i2 < 64; ++i2) {
            FBODY(qa, 2 * i2);
            FBODY(qb, 2 * i2 + 1);
        }
    }

    if (lane63) g_shape[b] = rp2[3];   // R'(255, 510)

    asm volatile("s_waitcnt vmcnt(0)" ::: "memory");   // all W stores retired

    // ================= backward =================
    float Ep1[4], Ep2[4];              // E at d+1 / d+2
    float wu1[4], wl1[4];              // weights at d+1
    float wdk1[4], wd2[4];             // wd at d+1 / d+2
#pragma unroll
    for (int r = 0; r < 4; ++r) {
        Ep1[r] = 0.0f; Ep2[r] = 0.0f;
        wu1[r] = 0.0f; wl1[r] = 0.0f; wdk1[r] = 0.0f; wd2[r] = 0.0f;
    }
    float se1r = 0.0f, se2r = 0.0f;    // raw shfl: E[row0+4] at d+1 / d+2
    float su1r = 0.0f;                 // raw shfl: wu[row0+4] at d+1
    float sd1r = 0.0f, sd2r = 0.0f;    // raw shfl: wd[row0+4] at d+1 / d+2
    float sumE = 0.0f, sumEw = 0.0f;

    auto BBODY = [&](uint4 (&wq)[4], int dq) {
#pragma unroll
        for (int qq = 3; qq >= 0; --qq) {
            const int d = dq * 4 + qq;
            float wuc[4], wlc[4], wdc[4];
#pragma unroll
            for (int r = 0; r < 4; ++r) {
                const uint32_t pk = (qq == 0) ? wq[r].x : (qq == 1) ? wq[r].y
                                  : (qq == 2) ? wq[r].z : wq[r].w;
                const float2 wv = unpackw(pk);
                wuc[r] = wv.x; wdc[r] = wv.y; wlc[r] = 1.0f - wv.x - wv.y;
            }
            float En[4];
#pragma unroll
            for (int r = 0; r < 3; ++r)
                En[r] = Ep1[r + 1] * wu1[r + 1] + Ep1[r] * wl1[r]
                      + Ep2[r + 1] * wd2[r + 1];
            const float seN = __shfl_down(En[0], 1);
            const float suN = __shfl_down(wuc[0], 1);
            const float sdN = __shfl_down(wdc[0], 1);
            {   // row 3 — boundary, consumed last (shfl slack)
                const float eu1 = lane63 ? 0.0f : se1r;
                const float wuu = lane63 ? 0.0f : su1r;
                const float eu2 = lane63 ? 0.0f : se2r;
                const float wdu = lane63 ? 0.0f : sd2r;
                En[3] = eu1 * wuu + Ep1[3] * wl1[3] + eu2 * wdu;
            }
            if (d == 510) En[3] = lane63 ? 1.0f : En[3];   // seed (255,255)
#pragma unroll
            for (int r = 0; r < 4; ++r) {
                const bool valid = (unsigned)(d - (row0 + r)) < 256u;
                const float Eg = valid ? En[r] : 0.0f;
                En[r] = Eg;
                sumE += Eg;
                const float fw = (float)(2 * (row0 + r) - d);
                sumEw = fmaf(Eg * fw, fw, sumEw);
            }
#pragma unroll
            for (int r = 0; r < 4; ++r) {
                Ep2[r] = Ep1[r]; Ep1[r] = En[r];
                wu1[r] = wuc[r]; wl1[r] = wlc[r];
                wd2[r] = wdk1[r]; wdk1[r] = wdc[r];
            }
            se2r = se1r; se1r = seN;
            sd2r = sd1r; sd1r = sdN;
            su1r = suN;
        }
        const int dqn = (dq - 2 >= 0) ? (dq - 2) : 0;
#pragma unroll
        for (int r = 0; r < 4; ++r)
            wq[r] = W4[(size_t)dqn * TT + row0 + r];
    };

    {
        uint4 wqa[4], wqb[4];
#pragma unroll
        for (int r = 0; r < 4; ++r) {
            wqa[r] = W4[(size_t)(NDQ - 1) * TT + row0 + r];
            wqb[r] = W4[(size_t)(NDQ - 2) * TT + row0 + r];
        }
#pragma unroll 1
        for (int i2 = 0; i2 < 64; ++i2) {
            BBODY(wqa, 127 - 2 * i2);
            BBODY(wqb, 126 - 2 * i2);
        }
    }

    // wave reduction
#pragma unroll
    for (int off = 32; off; off >>= 1) {
        sumE  += __shfl_xor(sumE,  off);
        sumEw += __shfl_xor(sumEw, off);
    }
    if (lane == 0) { g_sumE[b] = sumE; g_sumEw[b] = sumEw; }
}

// ---------------------------------------------------------------------------
// Kernel 3: finalize scalar loss.
// ---------------------------------------------------------------------------
__global__ __launch_bounds__(128) void fin_kernel(float* __restrict__ out) {
    __shared__ float rs[128];
    __shared__ float rt2[128];
    const int b = threadIdx.x;

    const float shape = g_shape[b] * GLN2 * (1.0f / (float)TT);

    const float sE  = g_sumE[b]  * (1.0f / (float)TT);
    const float sEw = g_sumEw[b] * (1.0f / (float)TT) * (1.0f / (255.0f * 255.0f));
    const float temporal = sEw / fmaxf(sE, 1e-8f);

    rs[b]  = shape;
    rt2[b] = temporal;
    __syncthreads();
    for (int s = 64; s > 0; s >>= 1) {
        if (b < s) { rs[b] += rs[b + s]; rt2[b] += rt2[b + s]; }
        __syncthreads();
    }
    if (b == 0) {
        out[0] = 0.5f * (rs[0] * (1.0f / (float)BB)) + 0.5f * (rt2[0] * (1.0f / (float)BB));
    }
}

extern "C" void kernel_launch(void* const* d_in, const int* in_sizes, int n_in,
                              void* d_out, int out_size, void* d_ws, size_t ws_size,
                              hipStream_t stream) {
    (void)in_sizes; (void)n_in; (void)out_size; (void)d_ws; (void)ws_size;
    const float* preds   = (const float*)d_in[0];
    const float* targets = (const float*)d_in[1];
    float* out = (float*)d_out;

    dist_kernel<<<dim3(4, 4, BB), 256, 0, stream>>>(preds, targets);
    scan_kernel<<<BB, 64, 0, stream>>>();
    fin_kernel<<<1, 128, 0, stream>>>(out);
}